// Round 4
// baseline (82.179 us; speedup 1.0000x reference)
//
#include <hip/hip_runtime.h>
#include <math.h>

// Problem constants (fixed by harness)
#define NN   128
#define TT   1024
#define SS   1024
#define H1D  512
#define H2D  128
#define OUTD 8
#define TCH  16     // t-chunks (TC=64 each); 2 chunks per block
#define TC   64
#define SPT  8      // s-values per thread

// ws layout in floats (~17.6 MB)
#define OFF_RI   0                        // (re,im) partials [ch][n][s] float2
#define OFF_FREQ (TCH*NN*SS*2)            // 4194304: freq [n][s]
#define OFF_H1   (OFF_FREQ + NN*SS)       // 4325376: h1 [n][512] (post-sigmoid)

__device__ __forceinline__ float cos_rev(float r) { return __builtin_amdgcn_cosf(r); } // cos(2*pi*r)
__device__ __forceinline__ float sin_rev(float r) { return __builtin_amdgcn_sinf(r); } // sin(2*pi*r)

// ---------------------------------------------------------------------------
// Kernel 1: partial NUDFT. Block = (chunk-pair c, batch n), 256 threads =
// 2 t-halves x 128 s-lanes. Thread owns 8 consecutive s: one hw sincos for
// base s, 7 angle-addition rotations by (cos 2*pi*d, sin 2*pi*d) from LDS.
// Exact mod-1: frac(s*day) == frac(s*frac(day)); product split hi+lo by FMA.
// Plain C body (bit-identical to validated round-2 version).
// ---------------------------------------------------------------------------
__global__ __launch_bounds__(256) void k_nudft(const float* __restrict__ inp,
                                               float* __restrict__ ws) {
    const int c   = blockIdx.x;    // 0..7 (pair of t-chunks)
    const int n   = blockIdx.y;    // 0..127
    const int tid = threadIdx.x;
    const int th  = tid >> 7;      // t-half 0/1
    const int sl  = tid & 127;     // s-lane

    __shared__ float4 sh[128];     // {frac(day), x, cos(2pi d), sin(2pi d)}
    if (tid < 128) {
        const float* p = inp + (size_t)(n * TT + c * 128 + tid) * 3;
        const float x  = p[0];
        const float d  = p[2];
        const float df = d - floorf(d);            // exact for |d| < 2^23
        sh[tid] = make_float4(df, x, cos_rev(df), sin_rev(df));
    }
    __syncthreads();

    const float s0f = (float)(sl * SPT);
    float2 acc[SPT];
#pragma unroll
    for (int q = 0; q < SPT; ++q) acc[q] = make_float2(0.f, 0.f);

#pragma unroll 2
    for (int i = 0; i < TC; ++i) {
        const float4 v = sh[th * TC + i];          // broadcast read
        const float p   = s0f * v.x;
        const float plo = fmaf(s0f, v.x, -p);      // exact product residual
        const float r   = (p - floorf(p)) + plo;
        float2 cs;
        cs.x = cos_rev(r);
        cs.y = sin_rev(r);
#pragma unroll
        for (int q = 0; q < SPT; ++q) {
            acc[q].x = fmaf(v.y, cs.x, acc[q].x);
            acc[q].y = fmaf(v.y, cs.y, acc[q].y);
            if (q < SPT - 1) {
                const float nc = fmaf(cs.y, -v.w, cs.x * v.z);
                const float ns = fmaf(cs.x,  v.w, cs.y * v.z);
                cs.x = nc; cs.y = ns;
            }
        }
    }

    const int ch = c * 2 + th;     // partial-chunk index 0..15
    float4* RI = (float4*)(ws + OFF_RI) +
                 ((((size_t)(ch * NN + n)) * SS + sl * SPT) >> 1);
#pragma unroll
    for (int q = 0; q < SPT / 2; ++q)
        RI[q] = make_float4(acc[2*q].x, acc[2*q].y, acc[2*q+1].x, acc[2*q+1].y);
}

// ---------------------------------------------------------------------------
// Kernel 2: combine t-chunk partials -> frequential = sqrt(re^2 + im^2)
// ---------------------------------------------------------------------------
__global__ __launch_bounds__(256) void k_combine1(float* __restrict__ ws) {
    const int idx = blockIdx.x * 256 + threadIdx.x;   // = n*SS + s
    const float2* P = (const float2*)(ws + OFF_RI);
    float re = 0.f, im = 0.f;
#pragma unroll
    for (int tc = 0; tc < TCH; ++tc) {
        const float2 v = P[(size_t)tc * (NN * SS) + idx];
        re += v.x; im += v.y;
    }
    ws[OFF_FREQ + idx] = sqrtf(fmaf(re, re, im * im));
}

// ---------------------------------------------------------------------------
// Kernel 3: layer-1 GEMM + bias + sigmoid, wave-per-j (lanes along k):
// raw W1 rows read coalesced float4 (no transpose), freq staged in LDS,
// 64-lane shuffle-tree reduce. Full K -> writes h1 directly.
// Grid (16 n-groups x 16 j-slices), 256 thr; wave handles 8 j for 8 n.
// ---------------------------------------------------------------------------
__global__ __launch_bounds__(256) void k_l1(const float* __restrict__ W1,
                                            const float* __restrict__ b1,
                                            float* __restrict__ ws) {
    const int ng  = blockIdx.x;    // 8 n per block
    const int js  = blockIdx.y;    // 32 j per block
    const int wid = threadIdx.x >> 6, lane = threadIdx.x & 63;

    __shared__ float4 fq[8][256];  // 8 n-rows x 1024 k (32 KB)
    const float4* FQ4 = (const float4*)(ws + OFF_FREQ);
#pragma unroll
    for (int v = 0; v < 8; ++v) {
        const int idx = v * 256 + threadIdx.x;
        fq[idx >> 8][idx & 255] = FQ4[(size_t)(ng * 8 + (idx >> 8)) * 256 + (idx & 255)];
    }
    __syncthreads();

    const float4* W14 = (const float4*)W1;
    float* H1 = ws + OFF_H1;
    for (int jj = 0; jj < 8; ++jj) {
        const int j = js * 32 + wid * 8 + jj;
        float a[8] = {0.f, 0.f, 0.f, 0.f, 0.f, 0.f, 0.f, 0.f};
#pragma unroll
        for (int pass = 0; pass < 4; ++pass) {
            const float4 w = W14[(size_t)j * 256 + pass * 64 + lane];  // coalesced
#pragma unroll
            for (int m = 0; m < 8; ++m) {
                const float4 q = fq[m][pass * 64 + lane];
                a[m] = fmaf(w.x, q.x, fmaf(w.y, q.y, fmaf(w.z, q.z, fmaf(w.w, q.w, a[m]))));
            }
        }
#pragma unroll
        for (int m = 0; m < 8; ++m) {
            float s = a[m];
#pragma unroll
            for (int off = 32; off > 0; off >>= 1) s += __shfl_xor(s, off, 64);
            if (lane == m)
                H1[(size_t)(ng * 8 + m) * H1D + j] = 1.0f / (1.0f + __expf(-(s + b1[j])));
        }
    }
}

// ---------------------------------------------------------------------------
// Kernel 4: layers 2+3, one block per batch. Wave-per-j on raw W2 (coalesced
// float4, lanes along k) + shuffle reduce; then wave 0 does the 8 outputs.
// ---------------------------------------------------------------------------
__global__ __launch_bounds__(256) void k_tail(const float* __restrict__ W2,
                                              const float* __restrict__ b2,
                                              const float* __restrict__ W3,
                                              const float* __restrict__ b3,
                                              const float* __restrict__ ws,
                                              float* __restrict__ out) {
    const int n   = blockIdx.x;
    const int tid = threadIdx.x;
    const int wid = tid >> 6, lane = tid & 63;

    __shared__ float4 h1s[128];    // h1 row (512 floats)
    __shared__ float2 h2s2[64];    // h2 row (128 floats)
    float* h2s = (float*)h2s2;
    if (tid < 128) h1s[tid] = ((const float4*)(ws + OFF_H1))[(size_t)n * 128 + tid];
    __syncthreads();

    const float4* W24 = (const float4*)W2;
    for (int jj = 0; jj < 32; ++jj) {
        const int j = wid * 32 + jj;
        float a = 0.f;
#pragma unroll
        for (int pass = 0; pass < 2; ++pass) {
            const float4 w = W24[(size_t)j * 128 + pass * 64 + lane];  // coalesced
            const float4 h = h1s[pass * 64 + lane];
            a = fmaf(w.x, h.x, fmaf(w.y, h.y, fmaf(w.z, h.z, fmaf(w.w, h.w, a))));
        }
#pragma unroll
        for (int off = 32; off > 0; off >>= 1) a += __shfl_xor(a, off, 64);
        if (lane == 0) h2s[j] = 1.0f / (1.0f + __expf(-(a + b2[j])));
    }
    __syncthreads();

    if (wid == 0) {
#pragma unroll
        for (int j = 0; j < OUTD; ++j) {
            const float2 w = ((const float2*)W3)[j * 64 + lane];
            const float2 h = h2s2[lane];
            float a = fmaf(w.x, h.x, w.y * h.y);
#pragma unroll
            for (int off = 32; off > 0; off >>= 1) a += __shfl_xor(a, off, 64);
            if (lane == 0) out[n * OUTD + j] = a + b3[j];
        }
    }
}

extern "C" void kernel_launch(void* const* d_in, const int* in_sizes, int n_in,
                              void* d_out, int out_size, void* d_ws, size_t ws_size,
                              hipStream_t stream) {
    (void)in_sizes; (void)n_in; (void)out_size; (void)ws_size;
    const float* inp = (const float*)d_in[0];
    const float* W1  = (const float*)d_in[1];
    const float* b1  = (const float*)d_in[2];
    const float* W2  = (const float*)d_in[3];
    const float* b2  = (const float*)d_in[4];
    const float* W3  = (const float*)d_in[5];
    const float* b3  = (const float*)d_in[6];
    float* out = (float*)d_out;
    float* ws  = (float*)d_ws;

    k_nudft   <<<dim3(8, NN),   dim3(256), 0, stream>>>(inp, ws);
    k_combine1<<<dim3(512),     dim3(256), 0, stream>>>(ws);
    k_l1      <<<dim3(16, 16),  dim3(256), 0, stream>>>(W1, b1, ws);
    k_tail    <<<dim3(NN),      dim3(256), 0, stream>>>(W2, b2, W3, b3, ws, out);
}

// Round 5
// 68.992 us; speedup vs baseline: 1.1911x; 1.1911x over previous
//
#include <hip/hip_runtime.h>
#include <math.h>

// Problem constants (fixed by harness)
#define NN   128
#define TT   1024
#define SS   1024
#define H1D  512
#define H2D  128
#define OUTD 8
#define TCH  4      // t-chunks for NUDFT split (round-1 proven config)
#define TC   256    // t per chunk

// ws layout in floats (~6 MB)
#define OFF_RE   0
#define OFF_IM   (TCH*NN*SS)                  //  524288
#define OFF_FREQ (2*TCH*NN*SS)                // 1048576
#define OFF_H1   (OFF_FREQ + NN*SS)           // 1179648 (end 1245184)

__device__ __forceinline__ float cos_rev(float r) { return __builtin_amdgcn_cosf(r); } // cos(2*pi*r)
__device__ __forceinline__ float sin_rev(float r) { return __builtin_amdgcn_sinf(r); } // sin(2*pi*r)

// ---------------------------------------------------------------------------
// Kernel 1: partial NUDFT — BIT-IDENTICAL to round-1 version (57.2 us best).
// Block = (t-chunk tc, batch n). Each thread owns 4 consecutive s; one hw
// sincos for base s, 3 angle-addition rotations via per-t (cos,sin) from LDS.
// ---------------------------------------------------------------------------
__global__ __launch_bounds__(256) void k_nudft(const float* __restrict__ inp,
                                               float* __restrict__ ws) {
    const int tc  = blockIdx.x;   // 0..3
    const int n   = blockIdx.y;   // 0..127
    const int tid = threadIdx.x;  // 0..255

    __shared__ float4 sh[TC];     // {frac(day), x, cos(2pi d), sin(2pi d)}
    {
        const int t = tc * TC + tid;
        const float* p = inp + (size_t)(n * TT + t) * 3;
        const float x  = p[0];
        const float d  = p[2];
        const float df = d - floorf(d);            // exact for |d| < 2^23
        sh[tid] = make_float4(df, x, cos_rev(df), sin_rev(df));
    }
    __syncthreads();

    const float s0f = (float)(tid * 4);
    float re0 = 0.f, re1 = 0.f, re2 = 0.f, re3 = 0.f;
    float im0 = 0.f, im1 = 0.f, im2 = 0.f, im3 = 0.f;

#pragma unroll 2
    for (int i = 0; i < TC; ++i) {
        const float4 v = sh[i];                    // broadcast read
        const float p   = s0f * v.x;
        const float plo = fmaf(s0f, v.x, -p);      // exact product residual
        const float r   = (p - floorf(p)) + plo;
        float c  = cos_rev(r);
        float sn = sin_rev(r);
        re0 = fmaf(v.y, c, re0);  im0 = fmaf(v.y, sn, im0);
        float c2  = fmaf(-sn, v.w, c * v.z);
        float sn2 = fmaf( c,  v.w, sn * v.z);
        re1 = fmaf(v.y, c2, re1); im1 = fmaf(v.y, sn2, im1);
        float c3  = fmaf(-sn2, v.w, c2 * v.z);
        float sn3 = fmaf( c2,  v.w, sn2 * v.z);
        re2 = fmaf(v.y, c3, re2); im2 = fmaf(v.y, sn3, im2);
        float c4  = fmaf(-sn3, v.w, c3 * v.z);
        float sn4 = fmaf( c3,  v.w, sn3 * v.z);
        re3 = fmaf(v.y, c4, re3); im3 = fmaf(v.y, sn4, im3);
    }

    const size_t base4 = (((size_t)(tc * NN + n)) * SS + tid * 4) >> 2;
    float4* RE = (float4*)(ws + OFF_RE);
    float4* IM = (float4*)(ws + OFF_IM);
    RE[base4] = make_float4(re0, re1, re2, re3);
    IM[base4] = make_float4(im0, im1, im2, im3);
}

// ---------------------------------------------------------------------------
// Kernel 2: combine t-chunk partials -> frequential = sqrt(re^2 + im^2)
// (bit-identical to round 1)
// ---------------------------------------------------------------------------
__global__ __launch_bounds__(256) void k_combine1(float* __restrict__ ws) {
    const int tid = blockIdx.x * 256 + threadIdx.x;   // 0..131071 (= n*SS + s)
    const int n = tid >> 10, s = tid & 1023;
    float re = 0.f, im = 0.f;
    for (int tc = 0; tc < TCH; ++tc) {
        const size_t o = ((size_t)(tc * NN + n)) * SS + s;
        re += ws[OFF_RE + o];
        im += ws[OFF_IM + o];
    }
    ws[OFF_FREQ + tid] = sqrtf(fmaf(re, re, im * im));
}

// ---------------------------------------------------------------------------
// Kernel 3 (THE ONE CHANGE vs round 1): layer-1 GEMM + bias + sigmoid,
// wave-per-j with lanes along k: raw W1 rows read coalesced float4 (no
// transpose), freq tile staged in LDS, 64-lane shuffle-tree reduce, full K.
// Replaces round-1's split-K l1p (uncoalesced W1: 64 lines/load) + l1c.
// Grid (16 n-groups x 16 j-slices), 256 thr; each wave: 8 j x 8 n.
// ---------------------------------------------------------------------------
__global__ __launch_bounds__(256) void k_l1(const float* __restrict__ W1,
                                            const float* __restrict__ b1,
                                            float* __restrict__ ws) {
    const int ng  = blockIdx.x;    // 8 n per block
    const int js  = blockIdx.y;    // 32 j per block
    const int wid = threadIdx.x >> 6, lane = threadIdx.x & 63;

    __shared__ float4 fq[8][256];  // 8 n-rows x 1024 k (32 KB)
    const float4* FQ4 = (const float4*)(ws + OFF_FREQ);
#pragma unroll
    for (int v = 0; v < 8; ++v) {
        const int idx = v * 256 + threadIdx.x;
        fq[idx >> 8][idx & 255] = FQ4[(size_t)(ng * 8 + (idx >> 8)) * 256 + (idx & 255)];
    }
    __syncthreads();

    const float4* W14 = (const float4*)W1;
    float* H1 = ws + OFF_H1;
    for (int jj = 0; jj < 8; ++jj) {
        const int j = js * 32 + wid * 8 + jj;
        float a[8] = {0.f, 0.f, 0.f, 0.f, 0.f, 0.f, 0.f, 0.f};
#pragma unroll
        for (int pass = 0; pass < 4; ++pass) {
            const float4 w = W14[(size_t)j * 256 + pass * 64 + lane];  // coalesced
#pragma unroll
            for (int m = 0; m < 8; ++m) {
                const float4 q = fq[m][pass * 64 + lane];
                a[m] = fmaf(w.x, q.x, fmaf(w.y, q.y, fmaf(w.z, q.z, fmaf(w.w, q.w, a[m]))));
            }
        }
#pragma unroll
        for (int m = 0; m < 8; ++m) {
            float s = a[m];
#pragma unroll
            for (int off = 32; off > 0; off >>= 1) s += __shfl_xor(s, off, 64);
            if (lane == m)
                H1[(size_t)(ng * 8 + m) * H1D + j] = 1.0f / (1.0f + __expf(-(s + b1[j])));
        }
    }
}

// ---------------------------------------------------------------------------
// Kernel 4: fused layers 2+3 — bit-identical to round 1 (reads post-sigmoid
// h1 from OFF_H1, no b1/partial combine needed anymore).
// ---------------------------------------------------------------------------
__global__ __launch_bounds__(128) void k_l23(const float* __restrict__ W2,
                                             const float* __restrict__ b2,
                                             const float* __restrict__ W3,
                                             const float* __restrict__ b3,
                                             const float* __restrict__ ws,
                                             float* __restrict__ out) {
    const int n = blockIdx.x;
    const int j = threadIdx.x;   // 0..127

    __shared__ float4 h1l[128];  // h1 row (512 floats)
    __shared__ float  h2l[128];
    h1l[j] = ((const float4*)(ws + OFF_H1))[n * 128 + j];
    __syncthreads();

    const float4* W2v = (const float4*)W2;
    float a = b2[j];
#pragma unroll 4
    for (int k = 0; k < 128; ++k) {
        const float4 h = h1l[k];                    // broadcast
        const float4 w = W2v[(size_t)j * 128 + k];
        a = fmaf(h.x, w.x, fmaf(h.y, w.y, fmaf(h.z, w.z, fmaf(h.w, w.w, a))));
    }
    h2l[j] = 1.0f / (1.0f + __expf(-a));
    __syncthreads();

    if (j < OUTD) {
        float acc = b3[j];
        for (int q = 0; q < H2D; ++q) acc = fmaf(h2l[q], W3[j * H2D + q], acc);
        out[n * OUTD + j] = acc;
    }
}

extern "C" void kernel_launch(void* const* d_in, const int* in_sizes, int n_in,
                              void* d_out, int out_size, void* d_ws, size_t ws_size,
                              hipStream_t stream) {
    (void)in_sizes; (void)n_in; (void)out_size; (void)ws_size;
    const float* inp = (const float*)d_in[0];
    const float* W1  = (const float*)d_in[1];
    const float* b1  = (const float*)d_in[2];
    const float* W2  = (const float*)d_in[3];
    const float* b2  = (const float*)d_in[4];
    const float* W3  = (const float*)d_in[5];
    const float* b3  = (const float*)d_in[6];
    float* out = (float*)d_out;
    float* ws  = (float*)d_ws;

    k_nudft   <<<dim3(TCH, NN), dim3(256), 0, stream>>>(inp, ws);
    k_combine1<<<dim3(512),     dim3(256), 0, stream>>>(ws);
    k_l1      <<<dim3(16, 16),  dim3(256), 0, stream>>>(W1, b1, ws);
    k_l23     <<<dim3(128),     dim3(128), 0, stream>>>(W2, b2, W3, b3, ws, out);
}